// Round 4
// baseline (384.382 us; speedup 1.0000x reference)
//
#include <hip/hip_runtime.h>
#include <hip/hip_bf16.h>

#define SEQ 512
#define BATCH 256
#define IN_DIM 150

#if __has_builtin(__builtin_amdgcn_exp2f)
__device__ __forceinline__ float fexp2(float x){ return __builtin_amdgcn_exp2f(x); }
#else
__device__ __forceinline__ float fexp2(float x){ return exp2f(x); }
#endif
#if __has_builtin(__builtin_amdgcn_rcpf)
__device__ __forceinline__ float frcp(float x){ return __builtin_amdgcn_rcpf(x); }
#else
__device__ __forceinline__ float frcp(float x){ return 1.0f/(x); }
#endif

#define NEG_LOG2E -1.44269504088896341f
#define TWO_LOG2E  2.88539008177792681f

// DPP cross-lane move. quad_perm: 0xB1 = xor1, 0x4E = xor2, 0x1B = xor3.
// 0x114 = row_shr:4 (lane i <- lane i-4 within 16-lane row; bound lanes -> 0).
template<int CTRL>
__device__ __forceinline__ float dppmov(float v){
    return __int_as_float(__builtin_amdgcn_mov_dpp(__float_as_int(v), CTRL, 0xF, 0xF, true));
}

// ---------------------------------------------------------------------------
// Kernel 1: layer-0 input projection, v2.
// Coalesced: block stages 64 rows of x (64x150 f32) + all weights into LDS,
// then 4 threads/row (thread q = hidden unit) each compute 4 gate dots.
// Output pre-scaled: i,f,o rows by -log2e; g rows by 2*log2e, so the scan's
// activations need no multiply: sigm = rcp(1+exp2(y)), tanh = 1-2*rcp(1+exp2(y)).
// ---------------------------------------------------------------------------
#define XROWS 64
__global__ __launch_bounds__(256) void xproj2(const float* __restrict__ x,
                                              const float* __restrict__ w,
                                              const float* __restrict__ bih,
                                              const float* __restrict__ bhh,
                                              float* __restrict__ xp)
{
    __shared__ float xs[XROWS*IN_DIM];   // 38400 B
    __shared__ float ws[16*IN_DIM];      //  9600 B
    __shared__ float bs[16];

    for (int i=threadIdx.x; i<16*IN_DIM; i+=256) ws[i] = w[i];
    if (threadIdx.x < 16) bs[threadIdx.x] = bih[threadIdx.x] + bhh[threadIdx.x];

    const size_t tilebase = (size_t)blockIdx.x * XROWS * IN_DIM;
    const float2* xg  = (const float2*)(x + tilebase);     // tile is contiguous
    float2*       xs2 = (float2*)xs;
    for (int i=threadIdx.x; i<XROWS*(IN_DIM/2); i+=256) xs2[i] = xg[i];
    __syncthreads();

    const int q = threadIdx.x & 3;       // hidden unit
    const int r = threadIdx.x >> 2;      // row within tile
    float acc0 = bs[q], acc1 = bs[4+q], acc2 = bs[8+q], acc3 = bs[12+q];
    const float* xr = xs + r*IN_DIM;
    const float* w0p = ws + (q    )*IN_DIM;
    const float* w1p = ws + (q+ 4 )*IN_DIM;
    const float* w2p = ws + (q+ 8 )*IN_DIM;
    const float* w3p = ws + (q+12 )*IN_DIM;
#pragma unroll 5
    for (int d=0; d<IN_DIM/2; ++d) {
        const float2 xv = *(const float2*)(xr  + 2*d);
        const float2 w0 = *(const float2*)(w0p + 2*d);
        const float2 w1 = *(const float2*)(w1p + 2*d);
        const float2 w2 = *(const float2*)(w2p + 2*d);
        const float2 w3 = *(const float2*)(w3p + 2*d);
        acc0 += xv.x*w0.x + xv.y*w0.y;
        acc1 += xv.x*w1.x + xv.y*w1.y;
        acc2 += xv.x*w2.x + xv.y*w2.y;
        acc3 += xv.x*w3.x + xv.y*w3.y;
    }
    const float4 o = make_float4(acc0*NEG_LOG2E, acc1*NEG_LOG2E,
                                 acc2*TWO_LOG2E, acc3*NEG_LOG2E);
    *(float4*)(xp + ((size_t)(blockIdx.x*XROWS + r))*16 + q*4) = o;
}

// ---------------------------------------------------------------------------
// Kernel 2: 4 layers wavefront-pipelined, 2 independent batch chains per wave
// (register-level ILP fills single-wave latency stalls; weights shared).
// lane = bb*16 + l*4 + k. Layer l computes t = tau - l. Handoff via row_shr:4
// DPP, own-layer h exchange via quad_perm DPP, xor-permuted weights.
// Weights pre-scaled by -log2e (i,f,o) / 2log2e (g) => activation = rcp(1+exp2).
// PHASE: 0 = head (t<0 masking + store guard), 1 = main (no masks, no clamps),
// 2 = tail (load clamp + store guard).
// ---------------------------------------------------------------------------
template<int PHASE>
__device__ __forceinline__ void lstm_step(
    float& h, float& c,
    float& a0, float& a1, float& a2, float& a3,
    float& s0, float& s1, float& s2, float& s3,
    const float4 xv, const int tau, const int l, const int k, const int b,
    const float wir[4][4], const float whp[4][4], const float bias[4],
    const float fcp[4], const float fcbv, float* __restrict__ out)
{
    const float x0 = (l==0) ? xv.x : s0;
    const float x1 = (l==0) ? xv.y : s1;
    const float x2 = (l==0) ? xv.z : s2;
    const float x3 = (l==0) ? xv.w : s3;
    float g0 = (bias[0] + ((wir[0][0]*x0 + wir[0][1]*x1) + (wir[0][2]*x2 + wir[0][3]*x3)))
             + ((whp[0][0]*a0 + whp[0][1]*a1) + (whp[0][2]*a2 + whp[0][3]*a3));
    float g1 = (bias[1] + ((wir[1][0]*x0 + wir[1][1]*x1) + (wir[1][2]*x2 + wir[1][3]*x3)))
             + ((whp[1][0]*a0 + whp[1][1]*a1) + (whp[1][2]*a2 + whp[1][3]*a3));
    float g2 = (bias[2] + ((wir[2][0]*x0 + wir[2][1]*x1) + (wir[2][2]*x2 + wir[2][3]*x3)))
             + ((whp[2][0]*a0 + whp[2][1]*a1) + (whp[2][2]*a2 + whp[2][3]*a3));
    float g3 = (bias[3] + ((wir[3][0]*x0 + wir[3][1]*x1) + (wir[3][2]*x2 + wir[3][3]*x3)))
             + ((whp[3][0]*a0 + whp[3][1]*a1) + (whp[3][2]*a2 + whp[3][3]*a3));
    const float ig = frcp(1.0f + fexp2(g0));
    const float fg = frcp(1.0f + fexp2(g1));
    const float rg = frcp(1.0f + fexp2(g2));
    const float og = frcp(1.0f + fexp2(g3));
    const float gg = __builtin_fmaf(-2.0f, rg, 1.0f);
    c = __builtin_fmaf(fg, c, ig*gg);
    const float rc = frcp(1.0f + fexp2(TWO_LOG2E*c));
    h = og * __builtin_fmaf(-2.0f, rc, 1.0f);
    const int t = tau - l;
    if (PHASE==0) { if (t < 0) { h = 0.f; c = 0.f; } }
    a0 = h;
    a1 = dppmov<0xB1>(h);
    a2 = dppmov<0x4E>(h);
    a3 = dppmov<0x1B>(h);
    s0 = dppmov<0x114>(a0);
    s1 = dppmov<0x114>(a1);
    s2 = dppmov<0x114>(a2);
    s3 = dppmov<0x114>(a3);
    bool doSt = (l==3) && (k==0);
    if (PHASE==0) doSt = doSt && (t >= 0);
    if (PHASE==2) doSt = doSt && (t < SEQ);
    if (doSt) out[(size_t)t*BATCH + b] =
        fcbv + ((fcp[0]*a0 + fcp[1]*a1) + (fcp[2]*a2 + fcp[3]*a3));
}

__global__ __launch_bounds__(64) void lstm_pipe2(
    const float* __restrict__ xp,
    const float* __restrict__ w_hh0,
    const float* __restrict__ w_ih_r,
    const float* __restrict__ w_hh_r,
    const float* __restrict__ b_ih_r,
    const float* __restrict__ b_hh_r,
    const float* __restrict__ fcw,
    const float* __restrict__ fcb,
    float* __restrict__ out)
{
    const int lane = threadIdx.x;
    const int k  = lane & 3;
    const int l  = (lane >> 2) & 3;
    const int bb = lane >> 4;

    // shared (per-lane) weights, pre-scaled; xor-permuted in m
    const float* whh = (l==0) ? w_hh0 : (w_hh_r + (size_t)(l-1)*64);
    float whp[4][4], wir[4][4], bias[4], fcp[4];
    const float sfac[4] = {NEG_LOG2E, NEG_LOG2E, TWO_LOG2E, NEG_LOG2E};
#pragma unroll
    for (int j=0;j<4;++j) {
        const int row = j*4+k;
        const float sj = sfac[j];
#pragma unroll
        for (int m=0;m<4;++m) whp[j][m] = sj*whh[row*4 + (k^m)];
        if (l==0) {
            bias[j] = 0.f;                      // folded into xp (pre-scaled)
#pragma unroll
            for (int m=0;m<4;++m) wir[j][m] = (m==j) ? 1.f : 0.f;  // identity, unscaled
        } else {
            const float* wih = w_ih_r + (size_t)(l-1)*64;
            bias[j] = sj*(b_ih_r[(l-1)*16+row] + b_hh_r[(l-1)*16+row]);
#pragma unroll
            for (int m=0;m<4;++m) wir[j][m] = sj*wih[row*4 + (k^m)];
        }
    }
#pragma unroll
    for (int m=0;m<4;++m) fcp[m] = fcw[k^m];
    const float fcbv = fcb[0];

    // two chains: batch b = blockIdx*8 + g*4 + bb
    int bidx[2];
    const float* xbase[2];
#pragma unroll
    for (int g=0; g<2; ++g) {
        bidx[g]  = blockIdx.x*8 + g*4 + bb;
        xbase[g] = xp + (size_t)bidx[g]*16 + k*4;
    }
    float H[2]={0.f,0.f}, C[2]={0.f,0.f};
    float A0[2]={0,0},A1[2]={0,0},A2[2]={0,0},A3[2]={0,0};
    float S0[2]={0,0},S1[2]={0,0},S2[2]={0,0},S3[2]={0,0};

    float4 BA[2][4], BB[2][4];

#define LDX(g,t)       (*(const float4*)(xbase[g] + (size_t)(t)*(BATCH*16)))
#define LDXC(g,t)      (*(const float4*)(xbase[g] + (size_t)((t)<SEQ-1?(t):SEQ-1)*(BATCH*16)))
#define STEP(P,g,buf,tau_) lstm_step<P>(H[g],C[g],A0[g],A1[g],A2[g],A3[g], \
        S0[g],S1[g],S2[g],S3[g], buf, tau_, l, k, bidx[g], wir, whp, bias, fcp, fcbv, out)

#pragma unroll
    for (int g=0; g<2; ++g) {
#pragma unroll
        for (int j=0;j<4;++j) BA[g][j] = LDX(g, j);
    }

    // ---- head: tau 0..7, with t<0 masking ----
    {
        const int tau = 0;
#pragma unroll
        for (int g=0; g<2; ++g) { BB[g][0]=LDX(g,tau+4); BB[g][1]=LDX(g,tau+5); BB[g][2]=LDX(g,tau+6); BB[g][3]=LDX(g,tau+7); }
#pragma unroll
        for (int j=0;j<4;++j)
#pragma unroll
            for (int g=0; g<2; ++g) STEP(0, g, BA[g][j], tau+j);
#pragma unroll
        for (int g=0; g<2; ++g) { BA[g][0]=LDX(g,tau+8); BA[g][1]=LDX(g,tau+9); BA[g][2]=LDX(g,tau+10); BA[g][3]=LDX(g,tau+11); }
#pragma unroll
        for (int j=0;j<4;++j)
#pragma unroll
            for (int g=0; g<2; ++g) STEP(0, g, BB[g][j], tau+4+j);
    }

    // ---- main: tau 8..495, no masks, no clamps (max load index 506 < 512) ----
    for (int tau=8; tau<496; tau+=8) {
#pragma unroll
        for (int g=0; g<2; ++g) { BB[g][0]=LDX(g,tau+4); BB[g][1]=LDX(g,tau+5); BB[g][2]=LDX(g,tau+6); BB[g][3]=LDX(g,tau+7); }
#pragma unroll
        for (int j=0;j<4;++j)
#pragma unroll
            for (int g=0; g<2; ++g) STEP(1, g, BA[g][j], tau+j);
#pragma unroll
        for (int g=0; g<2; ++g) { BA[g][0]=LDX(g,tau+8); BA[g][1]=LDX(g,tau+9); BA[g][2]=LDX(g,tau+10); BA[g][3]=LDX(g,tau+11); }
#pragma unroll
        for (int j=0;j<4;++j)
#pragma unroll
            for (int g=0; g<2; ++g) STEP(1, g, BB[g][j], tau+4+j);
    }

    // ---- tail: tau 496..519, clamped loads + store guard ----
    for (int tau=496; tau<520; tau+=8) {
#pragma unroll
        for (int g=0; g<2; ++g) { BB[g][0]=LDXC(g,tau+4); BB[g][1]=LDXC(g,tau+5); BB[g][2]=LDXC(g,tau+6); BB[g][3]=LDXC(g,tau+7); }
#pragma unroll
        for (int j=0;j<4;++j)
#pragma unroll
            for (int g=0; g<2; ++g) STEP(2, g, BA[g][j], tau+j);
#pragma unroll
        for (int g=0; g<2; ++g) { BA[g][0]=LDXC(g,tau+8); BA[g][1]=LDXC(g,tau+9); BA[g][2]=LDXC(g,tau+10); BA[g][3]=LDXC(g,tau+11); }
#pragma unroll
        for (int j=0;j<4;++j)
#pragma unroll
            for (int g=0; g<2; ++g) STEP(2, g, BB[g][j], tau+4+j);
    }
#undef LDX
#undef LDXC
#undef STEP
}

// ---------------------------------------------------------------------------
extern "C" void kernel_launch(void* const* d_in, const int* in_sizes, int n_in,
                              void* d_out, int out_size, void* d_ws, size_t ws_size,
                              hipStream_t stream)
{
    const float* x      = (const float*)d_in[0];
    const float* w_ih0  = (const float*)d_in[1];
    const float* w_hh0  = (const float*)d_in[2];
    const float* b_ih0  = (const float*)d_in[3];
    const float* b_hh0  = (const float*)d_in[4];
    const float* w_ih_r = (const float*)d_in[5];   // (3,16,4)
    const float* w_hh_r = (const float*)d_in[6];   // (3,16,4)
    const float* b_ih_r = (const float*)d_in[7];   // (3,16)
    const float* b_hh_r = (const float*)d_in[8];   // (3,16)
    const float* fc_w   = (const float*)d_in[9];   // (1,4)
    const float* fc_b   = (const float*)d_in[10];  // (1,)
    float* out = (float*)d_out;

    float* xp0 = (float*)d_ws;                     // SEQ*BATCH*16 f32 = 8 MB

    xproj2<<<SEQ*BATCH/XROWS, 256, 0, stream>>>(x, w_ih0, b_ih0, b_hh0, xp0);
    lstm_pipe2<<<BATCH/8, 64, 0, stream>>>(xp0, w_hh0, w_ih_r, w_hh_r,
                                           b_ih_r, b_hh_r, fc_w, fc_b, out);
}

// Round 5
// 283.788 us; speedup vs baseline: 1.3545x; 1.3545x over previous
//
#include <hip/hip_runtime.h>
#include <hip/hip_bf16.h>

#define SEQ 512
#define BATCH 256
#define IN_DIM 150

#if __has_builtin(__builtin_amdgcn_exp2f)
__device__ __forceinline__ float fexp2(float x){ return __builtin_amdgcn_exp2f(x); }
#else
__device__ __forceinline__ float fexp2(float x){ return exp2f(x); }
#endif
#if __has_builtin(__builtin_amdgcn_rcpf)
__device__ __forceinline__ float frcp(float x){ return __builtin_amdgcn_rcpf(x); }
#else
__device__ __forceinline__ float frcp(float x){ return 1.0f/(x); }
#endif

#define NEG_LOG2E -1.44269504088896341f
#define TWO_LOG2E  2.88539008177792681f

// DPP cross-lane move. quad_perm: 0xB1 = xor1, 0x4E = xor2, 0x1B = xor3.
// 0x114 = row_shr:4 (lane i <- lane i-4 within 16-lane row; bound lanes -> 0).
template<int CTRL>
__device__ __forceinline__ float dppmov(float v){
    return __int_as_float(__builtin_amdgcn_mov_dpp(__float_as_int(v), CTRL, 0xF, 0xF, true));
}

// ---------------------------------------------------------------------------
// Kernel 1: layer-0 input projection, v3.
// 1 wave/block, 64 rows. x tile staged linearly via global_load_lds (39 instrs).
// lane = row. Weights stream through SGPRs (uniform address -> s_load, scalar
// cache, dual-issues with VALU). Per dim-pair: 1 ds_read_b64 + 16 paired FMAs.
// Output pre-scaled (i,f,o: -log2e; g: 2log2e) with biases folded.
// ---------------------------------------------------------------------------
__global__ __launch_bounds__(64) void xproj3(const float* __restrict__ x,
                                             const float* __restrict__ w,
                                             const float* __restrict__ bih,
                                             const float* __restrict__ bhh,
                                             float* __restrict__ xp)
{
    __shared__ float xs[64*IN_DIM];          // 38400 B
    const int lane = threadIdx.x;
    const size_t tilebase = (size_t)blockIdx.x * 64 * IN_DIM;   // in floats

    {   // async stage: 37 x 16B/lane + 2 x 4B/lane = 600 B/lane = 38400 B
        auto gsrc = (const __attribute__((address_space(1))) unsigned int*)(x + tilebase);
        auto ldst = (__attribute__((address_space(3))) unsigned int*)xs;
#pragma unroll
        for (int i=0;i<37;++i)
            __builtin_amdgcn_global_load_lds(gsrc + (size_t)i*256 + lane*4, ldst + i*256, 16, 0, 0);
#pragma unroll
        for (int i=0;i<2;++i)
            __builtin_amdgcn_global_load_lds(gsrc + 9472 + (size_t)i*64 + lane, ldst + 9472 + i*64, 4, 0, 0);
        asm volatile("s_waitcnt vmcnt(0)" ::: "memory");
    }

    float2 acc[16];
#pragma unroll
    for (int g=0; g<16; ++g) acc[g] = make_float2(0.f, 0.f);
    const float* xr = xs + lane*IN_DIM;
#pragma unroll 3
    for (int dq=0; dq<IN_DIM/2; ++dq) {
        const float2 xv = *(const float2*)(xr + 2*dq);
#pragma unroll
        for (int g=0; g<16; ++g) {
            const float2 wv = *(const float2*)(w + g*IN_DIM + 2*dq);  // uniform -> s_load
            acc[g].x = __builtin_fmaf(wv.x, xv.x, acc[g].x);
            acc[g].y = __builtin_fmaf(wv.y, xv.y, acc[g].y);
        }
    }
    float gate[16];
#pragma unroll
    for (int g=0; g<16; ++g)
        gate[g] = (acc[g].x + acc[g].y) + (bih[g] + bhh[g]);

    float* op = xp + ((size_t)(blockIdx.x*64 + lane))*16;
#pragma unroll
    for (int k=0;k<4;++k) {
        const float4 o = make_float4(gate[k]*NEG_LOG2E, gate[4+k]*NEG_LOG2E,
                                     gate[8+k]*TWO_LOG2E, gate[12+k]*NEG_LOG2E);
        *(float4*)(op + k*4) = o;
    }
}

// ---------------------------------------------------------------------------
// Kernel 2: 4 layers wavefront-pipelined, single chain (round-3 structure),
// transcendental diet: 8 trans/step instead of 10.
//   i*2log2e*tanh(g) = 2log2e*(E2-1)/((1+E0)(1+E2))   (one shared rcp)
//   o*tanh(c)        = (Ec-1)/((1+E3)(1+Ec))          (one shared rcp)
//   c' = 2log2e*c tracked directly (no mul before exp2 on the chain).
// ---------------------------------------------------------------------------
__global__ __launch_bounds__(64) void lstm_pipe3(
    const float* __restrict__ xp,
    const float* __restrict__ w_hh0,
    const float* __restrict__ w_ih_r,
    const float* __restrict__ w_hh_r,
    const float* __restrict__ b_ih_r,
    const float* __restrict__ b_hh_r,
    const float* __restrict__ fcw,
    const float* __restrict__ fcb,
    float* __restrict__ out)
{
    const int lane = threadIdx.x;
    const int k  = lane & 3;
    const int l  = (lane >> 2) & 3;
    const int bb = lane >> 4;
    const int b  = blockIdx.x*4 + bb;
    const bool isL0  = (l==0);
    const bool isOut = (l==3) && (k==0);

    const float* whh = isL0 ? w_hh0 : (w_hh_r + (size_t)(l-1)*64);
    float whp[4][4], wir[4][4], bias[4], fcp[4];
    const float sfac[4] = {NEG_LOG2E, NEG_LOG2E, TWO_LOG2E, NEG_LOG2E};
#pragma unroll
    for (int j=0;j<4;++j) {
        const int row = j*4+k;
        const float sj = sfac[j];
#pragma unroll
        for (int m=0;m<4;++m) whp[j][m] = sj*whh[row*4 + (k^m)];
        if (isL0) {
            bias[j] = 0.f;                      // folded into xp (pre-scaled)
#pragma unroll
            for (int m=0;m<4;++m) wir[j][m] = (m==j) ? 1.f : 0.f;
        } else {
            const float* wih = w_ih_r + (size_t)(l-1)*64;
            bias[j] = sj*(b_ih_r[(l-1)*16+row] + b_hh_r[(l-1)*16+row]);
#pragma unroll
            for (int m=0;m<4;++m) wir[j][m] = sj*wih[row*4 + (k^m)];
        }
    }
#pragma unroll
    for (int m=0;m<4;++m) fcp[m] = fcw[k^m];
    const float fcbv = fcb[0];

    const float* xbase = xp + (size_t)b*16 + k*4;

    float h=0.f, cp=0.f;                 // cp = 2*log2e*c
    float a0=0.f,a1=0.f,a2=0.f,a3=0.f;   // own-layer inputs (xor-permuted h)
    float s0=0.f,s1=0.f,s2=0.f,s3=0.f;   // prev-layer inputs (row-shifted)

    auto LDX = [&](int t)->float4 {      // unclamped
        return *(const float4*)(xbase + (size_t)t*(BATCH*16));
    };
    auto LDXC = [&](int t)->float4 {     // clamped (tail over-prefetch)
        const int tc = t < SEQ-1 ? t : SEQ-1;
        return *(const float4*)(xbase + (size_t)tc*(BATCH*16));
    };

    // phase: 0 head (t<0 masking + store t>=0), 1 main (no guards), 2 tail (t<SEQ)
    auto STEP = [&](float4 xv, int tau, int phase) __attribute__((always_inline)) {
        const float u0 = isL0 ? xv.x : s0;
        const float u1 = isL0 ? xv.y : s1;
        const float u2 = isL0 ? xv.z : s2;
        const float u3 = isL0 ? xv.w : s3;
        float g0 = (bias[0] + ((wir[0][0]*u0 + wir[0][1]*u1) + (wir[0][2]*u2 + wir[0][3]*u3)))
                 + ((whp[0][0]*a0 + whp[0][1]*a1) + (whp[0][2]*a2 + whp[0][3]*a3));
        float g1 = (bias[1] + ((wir[1][0]*u0 + wir[1][1]*u1) + (wir[1][2]*u2 + wir[1][3]*u3)))
                 + ((whp[1][0]*a0 + whp[1][1]*a1) + (whp[1][2]*a2 + whp[1][3]*a3));
        float g2 = (bias[2] + ((wir[2][0]*u0 + wir[2][1]*u1) + (wir[2][2]*u2 + wir[2][3]*u3)))
                 + ((whp[2][0]*a0 + whp[2][1]*a1) + (whp[2][2]*a2 + whp[2][3]*a3));
        float g3 = (bias[3] + ((wir[3][0]*u0 + wir[3][1]*u1) + (wir[3][2]*u2 + wir[3][3]*u3)))
                 + ((whp[3][0]*a0 + whp[3][1]*a1) + (whp[3][2]*a2 + whp[3][3]*a3));
        const float E0 = fexp2(g0);
        const float Ef = fexp2(g1);
        const float E2 = fexp2(g2);
        const float E3 = fexp2(g3);
        const float f   = frcp(1.0f + Ef);
        const float d02 = (1.0f + E0) * (1.0f + E2);
        const float r02 = frcp(d02);
        const float nig = __builtin_fmaf(TWO_LOG2E, E2, -TWO_LOG2E);
        const float ig2 = nig * r02;                  // = 2log2e * i * tanh(g)
        cp = __builtin_fmaf(f, cp, ig2);              // cp = 2log2e * c
        const float Ec = fexp2(cp);
        const float dh = (1.0f + E3) * (1.0f + Ec);
        const float rh = frcp(dh);
        h = (Ec - 1.0f) * rh;                         // = o * tanh(c)
        const int t = tau - l;
        if (phase==0) { if (t < 0) { h = 0.f; cp = 0.f; } }
        a0 = h;
        a1 = dppmov<0xB1>(h);
        a2 = dppmov<0x4E>(h);
        a3 = dppmov<0x1B>(h);
        s0 = dppmov<0x114>(a0);
        s1 = dppmov<0x114>(a1);
        s2 = dppmov<0x114>(a2);
        s3 = dppmov<0x114>(a3);
        bool doSt = isOut;
        if (phase==0) doSt = doSt && (t >= 0);
        if (phase==2) doSt = doSt && (t < SEQ);
        if (doSt) out[(size_t)t*BATCH + b] =
            fcbv + ((fcp[0]*a0 + fcp[1]*a1) + (fcp[2]*a2 + fcp[3]*a3));
    };

    float4 A0=LDX(0), A1=LDX(1), A2=LDX(2), A3=LDX(3);
    float4 B0,B1,B2,B3;

    // ---- head: tau 0..7 (t<0 masking; all load indices <= 11 are valid) ----
    {
        const int tau=0;
        B0=LDX(tau+4); B1=LDX(tau+5); B2=LDX(tau+6); B3=LDX(tau+7);
        STEP(A0,tau,0); STEP(A1,tau+1,0); STEP(A2,tau+2,0); STEP(A3,tau+3,0);
        A0=LDX(tau+8); A1=LDX(tau+9); A2=LDX(tau+10); A3=LDX(tau+11);
        STEP(B0,tau+4,0); STEP(B1,tau+5,0); STEP(B2,tau+6,0); STEP(B3,tau+7,0);
    }
    // ---- main: tau 8..495, no guards (max load index 506 < 512) ----
    for (int tau=8; tau<496; tau+=8) {
        B0=LDX(tau+4); B1=LDX(tau+5); B2=LDX(tau+6); B3=LDX(tau+7);
        STEP(A0,tau,1); STEP(A1,tau+1,1); STEP(A2,tau+2,1); STEP(A3,tau+3,1);
        A0=LDX(tau+8); A1=LDX(tau+9); A2=LDX(tau+10); A3=LDX(tau+11);
        STEP(B0,tau+4,1); STEP(B1,tau+5,1); STEP(B2,tau+6,1); STEP(B3,tau+7,1);
    }
    // ---- tail: tau 496..519, clamped loads + store guard ----
    for (int tau=496; tau<520; tau+=8) {
        B0=LDXC(tau+4); B1=LDXC(tau+5); B2=LDXC(tau+6); B3=LDXC(tau+7);
        STEP(A0,tau,2); STEP(A1,tau+1,2); STEP(A2,tau+2,2); STEP(A3,tau+3,2);
        A0=LDXC(tau+8); A1=LDXC(tau+9); A2=LDXC(tau+10); A3=LDXC(tau+11);
        STEP(B0,tau+4,2); STEP(B1,tau+5,2); STEP(B2,tau+6,2); STEP(B3,tau+7,2);
    }
}

// ---------------------------------------------------------------------------
extern "C" void kernel_launch(void* const* d_in, const int* in_sizes, int n_in,
                              void* d_out, int out_size, void* d_ws, size_t ws_size,
                              hipStream_t stream)
{
    const float* x      = (const float*)d_in[0];
    const float* w_ih0  = (const float*)d_in[1];
    const float* w_hh0  = (const float*)d_in[2];
    const float* b_ih0  = (const float*)d_in[3];
    const float* b_hh0  = (const float*)d_in[4];
    const float* w_ih_r = (const float*)d_in[5];   // (3,16,4)
    const float* w_hh_r = (const float*)d_in[6];   // (3,16,4)
    const float* b_ih_r = (const float*)d_in[7];   // (3,16)
    const float* b_hh_r = (const float*)d_in[8];   // (3,16)
    const float* fc_w   = (const float*)d_in[9];   // (1,4)
    const float* fc_b   = (const float*)d_in[10];  // (1,)
    float* out = (float*)d_out;

    float* xp0 = (float*)d_ws;                     // SEQ*BATCH*16 f32 = 8 MB

    xproj3<<<SEQ*BATCH/64, 64, 0, stream>>>(x, w_ih0, b_ih0, b_hh0, xp0);
    lstm_pipe3<<<BATCH/4, 64, 0, stream>>>(xp0, w_hh0, w_ih_r, w_hh_r,
                                           b_ih_r, b_hh_r, fc_w, fc_b, out);
}